// Round 4
// baseline (491.135 us; speedup 1.0000x reference)
//
#include <hip/hip_runtime.h>

typedef int v4i __attribute__((ext_vector_type(4)));

#define M_DIM 4096
#define N_DIM 11008
#define K_DIM 4096
#define KP    (K_DIM / 2)   // packed int32 elements per row (one byte each)
#define NKT   (K_DIM / 64)  // 64 K-tiles of 64

// ---------------------------------------------------------------------------
// SWAR sign-extend helpers
// ---------------------------------------------------------------------------
__device__ __forceinline__ unsigned pack2(int p) {
    int lo = (p << 28) >> 28;   // sign-extended low nibble
    int hi = (p << 24) >> 28;   // sign-extended high nibble
    return (unsigned)(lo & 0xFF) | ((unsigned)(hi & 0xFF) << 8);
}

__device__ __forceinline__ void unpack_group(int4 p, unsigned &slo, unsigned &shi) {
    unsigned c = ((unsigned)p.x & 0xFFu)
               | (((unsigned)p.y & 0xFFu) << 8)
               | (((unsigned)p.z & 0xFFu) << 16)
               | (((unsigned)p.w & 0xFFu) << 24);
    slo = (c & 0x0F0F0F0Fu) | ((c & 0x08080808u) * 30u);
    unsigned d = c >> 4;
    shi = (d & 0x0F0F0F0Fu) | ((d & 0x08080808u) * 30u);
}

// ---------------------------------------------------------------------------
// Pass 1 (merged, grid-stride): unpack BOTH x_q and weight into contiguous
// int8 regions of d_ws (A8 then B8).  16B load -> 8B store per element-group.
// ---------------------------------------------------------------------------
__global__ __launch_bounds__(256) void unpack_i4_all(
    const int* __restrict__ inA, const int* __restrict__ inB,
    uint2* __restrict__ out, int n4A, int n4tot)
{
    for (int idx = blockIdx.x * blockDim.x + threadIdx.x; idx < n4tot;
         idx += gridDim.x * blockDim.x) {
        int4 v;
        if (idx < n4A) v = ((const int4*)inA)[idx];
        else           v = ((const int4*)inB)[idx - n4A];
        unsigned d0 = pack2(v.x) | (pack2(v.y) << 16);
        unsigned d1 = pack2(v.z) | (pack2(v.w) << 16);
        out[idx] = make_uint2(d0, d1);
    }
}

// ---------------------------------------------------------------------------
// Pass 2: int8 GEMM, 256x256 tile, 512 threads = 8 waves (2 wm x 4 wn), each
// wave a 128x64 output via 8x4 tiles of mfma_i32_16x16x64_i8, BK=64.
//
// Sync skeleton (validated rounds 1-3): 4-buffer LDS rotation, depth-3
// K-tile prefetch, counted s_waitcnt vmcnt(8) ONCE per K-tile.
//
// NEW this round: CROSS-TILE REGISTER DOUBLE-BUFFERING.  Iteration kt:
//   s_waitcnt vmcnt(8) lgkmcnt(0)   // kt's 4 gload_lds landed (this wave);
//                                   // frag-reads of kt-1 drained (this wave)
//   sched_barrier(0); s_barrier     // => ALL waves: buf[kt] fully written,
//                                   //    NO pending ds_read on buf[kt-1]
//   issue 12x asm ds_read_b128 (frags of kt) -> set RD    // served by the
//   issue STAGE(kt+3) -> buf[(kt-1)&3]                    // LDS port WHILE
//   sched_barrier(0)                                      // MFMAs below run
//   32x MFMA on set MM = frags of kt-1 (already in regs, zero lgkm wait)
//
// Hazard proofs:
//  - Read-after-stage: vmcnt(8) at iter kt leaves only kt+1/kt+2's 8 loads
//    in flight -> kt's loads landed per-wave; barrier extends to all waves
//    before any ds_read of buf[kt&3].
//  - Stage-over-read: STAGE(kt+3) overwrites buf[(kt-1)&3].  Every wave
//    drained its frag-reads of kt-1 (lgkmcnt(0)) BEFORE arriving at the
//    iter-kt barrier; STAGE issues after that barrier -> no pending reads
//    anywhere on the buffer being overwritten.
//  - MFMA deps: set MM was drained by this iteration's lgkmcnt(0);
//    sched_barrier(0) (rule 18) stops the compiler hoisting MFMAs above it.
//
// LDS fragment-ordered (conflict-free, global_load_lds-compatible):
// buffer = 32 KB (A 16 KB | B 16 KB); chunk c = rowTile*64 + lane, 16 B.
// mfma_i32_16x16x64_i8 A/B frag: lane l holds row l&15, k-bytes (l>>4)*16.
// ---------------------------------------------------------------------------
__global__ __launch_bounds__(512, 2) void gemm_i8_kernel(
    const unsigned char* __restrict__ A8, const unsigned char* __restrict__ B8,
    const float* __restrict__ sx, const float* __restrict__ sw,
    float* __restrict__ out)
{
    __shared__ v4i smem[8192];                 // 128 KB: 4 buffers x (A 16KB | B 16KB)
    unsigned char* smemAll = (unsigned char*)smem;

    const int t    = threadIdx.x;
    const int lane = t & 63;
    const int w    = t >> 6;      // wave 0..7
    const int wm   = w >> 2;      // 0..1
    const int wn   = w & 3;       // 0..3

    // Bijective XCD swizzle: 688 blocks = 8 * 86 exact.
    const int orig = blockIdx.x;
    const int wgid = (orig & 7) * 86 + (orig >> 3);
    const int bx   = wgid >> 4;        // 0..42  (N tiles)
    const int by   = wgid & 15;        // 0..15  (M tiles)
    const int rowBase = by * 256;
    const int colBase = bx * 256;

    // Staging: thread t stages A-chunks {t, t+512} and B-chunks {t, t+512}.
    const int cA0 = t, cA1 = t + 512;
    const int rA0 = (cA0 >> 6) * 16 + (cA0 & 15);
    const int rA1 = (cA1 >> 6) * 16 + (cA1 & 15);
    const int qA0 = ((cA0 >> 4) & 3) * 16;
    const int qA1 = ((cA1 >> 4) & 3) * 16;

    const unsigned char* gA0 = A8 + (size_t)(rowBase + rA0) * K_DIM + qA0;
    const unsigned char* gA1 = A8 + (size_t)(rowBase + rA1) * K_DIM + qA1;
    const unsigned char* gB0 = B8 + (size_t)(colBase + rA0) * K_DIM + qA0;
    const unsigned char* gB1 = B8 + (size_t)(colBase + rA1) * K_DIM + qA1;

    const int oA0 = cA0 * 16;
    const int oA1 = cA1 * 16;
    const int oB0 = 16384 + cA0 * 16;
    const int oB1 = 16384 + cA1 * 16;

    // LDS byte offsets for asm ds_read_b128 (AS(3) pointer -> 32-bit offset).
    const unsigned ldsBase =
        (unsigned)(size_t)(__attribute__((address_space(3))) void*)smemAll;
    // A frag: ((wm*8 + mt)*64 + lane)*16 = wm*8192 + mt*1024 + lane*16
    // B frag: 16384 + ((wn*4 + nt)*64 + lane)*16 = 16384 + wn*4096 + nt*1024 + lane*16
    const unsigned aAddrBase = ldsBase + (unsigned)(wm * 8192 + lane * 16);
    const unsigned bAddrBase = ldsBase + (unsigned)(16384 + wn * 4096 + lane * 16);

    v4i acc[8][4] = {};
    v4i aFA[8], bFA[4], aFB[8], bFB[4];   // two named frag sets (rule 20)

#define STAGE_AB(S) do {                                                       \
    unsigned char* _sb = smemAll + (((S) & 3) << 15);                          \
    const int _kb = (S) * 64;                                                  \
    __builtin_amdgcn_global_load_lds(                                          \
        (const __attribute__((address_space(1))) void*)(gA0 + _kb),            \
        (__attribute__((address_space(3))) void*)(_sb + oA0), 16, 0, 0);       \
    __builtin_amdgcn_global_load_lds(                                          \
        (const __attribute__((address_space(1))) void*)(gA1 + _kb),            \
        (__attribute__((address_space(3))) void*)(_sb + oA1), 16, 0, 0);       \
    __builtin_amdgcn_global_load_lds(                                          \
        (const __attribute__((address_space(1))) void*)(gB0 + _kb),            \
        (__attribute__((address_space(3))) void*)(_sb + oB0), 16, 0, 0);       \
    __builtin_amdgcn_global_load_lds(                                          \
        (const __attribute__((address_space(1))) void*)(gB1 + _kb),            \
        (__attribute__((address_space(3))) void*)(_sb + oB1), 16, 0, 0);       \
} while (0)

    // 12 asm ds_read_b128 into a frag set; buffer selected by KT&3.
#define READ_FRAGS(AS, BS, KT) do {                                            \
    const unsigned _bo = ((unsigned)(KT) & 3u) << 15;                          \
    unsigned _aAddr = aAddrBase + _bo;                                         \
    unsigned _bAddr = bAddrBase + _bo;                                         \
    asm volatile("ds_read_b128 %0, %1 offset:0"    : "=v"(BS[0]) : "v"(_bAddr)); \
    asm volatile("ds_read_b128 %0, %1 offset:1024" : "=v"(BS[1]) : "v"(_bAddr)); \
    asm volatile("ds_read_b128 %0, %1 offset:2048" : "=v"(BS[2]) : "v"(_bAddr)); \
    asm volatile("ds_read_b128 %0, %1 offset:3072" : "=v"(BS[3]) : "v"(_bAddr)); \
    asm volatile("ds_read_b128 %0, %1 offset:0"    : "=v"(AS[0]) : "v"(_aAddr)); \
    asm volatile("ds_read_b128 %0, %1 offset:1024" : "=v"(AS[1]) : "v"(_aAddr)); \
    asm volatile("ds_read_b128 %0, %1 offset:2048" : "=v"(AS[2]) : "v"(_aAddr)); \
    asm volatile("ds_read_b128 %0, %1 offset:3072" : "=v"(AS[3]) : "v"(_aAddr)); \
    asm volatile("ds_read_b128 %0, %1 offset:4096" : "=v"(AS[4]) : "v"(_aAddr)); \
    asm volatile("ds_read_b128 %0, %1 offset:5120" : "=v"(AS[5]) : "v"(_aAddr)); \
    asm volatile("ds_read_b128 %0, %1 offset:6144" : "=v"(AS[6]) : "v"(_aAddr)); \
    asm volatile("ds_read_b128 %0, %1 offset:7168" : "=v"(AS[7]) : "v"(_aAddr)); \
} while (0)

#define MFMA_ALL(AS, BS) do {                                                  \
    __builtin_amdgcn_s_setprio(1);                                             \
    _Pragma("unroll")                                                          \
    for (int mt = 0; mt < 8; ++mt)                                             \
        _Pragma("unroll")                                                      \
        for (int nt = 0; nt < 4; ++nt)                                         \
            acc[mt][nt] = __builtin_amdgcn_mfma_i32_16x16x64_i8(               \
                AS[mt], BS[nt], acc[mt][nt], 0, 0, 0);                         \
    __builtin_amdgcn_s_setprio(0);                                             \
} while (0)

    // One pipeline step: wait (counted vmcnt + full lgkm drain), barrier,
    // issue next frag-reads + stage, then MFMA the previous tile's frags.
#define KITER(RA, RB, MA, MB, KT, VMC, DO_STAGE) do {                          \
    asm volatile("s_waitcnt vmcnt(" #VMC ") lgkmcnt(0)" ::: "memory");         \
    __builtin_amdgcn_sched_barrier(0);                                         \
    __builtin_amdgcn_s_barrier();                                              \
    READ_FRAGS(RA, RB, KT);                                                    \
    if (DO_STAGE) STAGE_AB((KT) + 3);                                          \
    __builtin_amdgcn_sched_barrier(0);                                         \
    MFMA_ALL(MA, MB);                                                          \
} while (0)

    // Prologue: stage K-tiles 0..2 (12 loads in flight); open buf0; read
    // tile-0 frags into set A; stage tile 3 (in flight back to 12).
    STAGE_AB(0); STAGE_AB(1); STAGE_AB(2);
    asm volatile("s_waitcnt vmcnt(8)" ::: "memory");
    __builtin_amdgcn_s_barrier();
    READ_FRAGS(aFA, bFA, 0);
    STAGE_AB(3);
    __builtin_amdgcn_sched_barrier(0);

    // Steady state: iters kt=1..60 stage kt+3 (tiles 4..63).  Parity:
    // odd kt reads into set B / MFMAs set A, even kt the reverse.
    for (int kt = 1; kt <= 59; kt += 2) {
        KITER(aFB, bFB, aFA, bFA, kt,     8, 1);
        KITER(aFA, bFA, aFB, bFB, kt + 1, 8, 1);
    }
    // Tail: no staging; vmcnt steps 8 -> 4 -> 0.
    KITER(aFB, bFB, aFA, bFA, 61, 8, 0);
    KITER(aFA, bFA, aFB, bFB, 62, 4, 0);
    KITER(aFB, bFB, aFA, bFA, 63, 0, 0);
    // Final tile's MFMA.
    asm volatile("s_waitcnt lgkmcnt(0)" ::: "memory");
    __builtin_amdgcn_sched_barrier(0);
    MFMA_ALL(aFB, bFB);

#undef STAGE_AB
#undef READ_FRAGS
#undef MFMA_ALL
#undef KITER

    // Epilogue. C/D layout (16x16): col = lane&15, row = (lane>>4)*4 + reg.
    const int ccol = lane & 15;
    const int crow = (lane >> 4) * 4;

    float xs[8][4];
    #pragma unroll
    for (int mt = 0; mt < 8; ++mt)
        #pragma unroll
        for (int r = 0; r < 4; ++r)
            xs[mt][r] = sx[rowBase + wm * 128 + mt * 16 + crow + r];

    #pragma unroll
    for (int nt = 0; nt < 4; ++nt) {
        const int gn = colBase + wn * 64 + nt * 16 + ccol;
        const float wsc = sw[gn];
        #pragma unroll
        for (int mt = 0; mt < 8; ++mt) {
            const int gm = rowBase + wm * 128 + mt * 16 + crow;
            #pragma unroll
            for (int r = 0; r < 4; ++r) {
                float v = (float)acc[mt][nt][r] * xs[mt][r] * wsc;
                out[(size_t)(gm + r) * N_DIM + gn] = v;
            }
        }
    }
}

// ---------------------------------------------------------------------------
// Fallback: fused unpack+GEMM (validated), used only if d_ws is too small
// for the int8 copies.
// ---------------------------------------------------------------------------
__global__ __launch_bounds__(256) void gemm_i4_fused_kernel(
    const int* __restrict__ Aq, const int* __restrict__ Bq,
    const float* __restrict__ sx, const float* __restrict__ sw,
    float* __restrict__ out)
{
    __shared__ v4i smem[1024];
    unsigned char* smemA = (unsigned char*)smem;
    unsigned char* smemB = smemA + 8192;

    const int t    = threadIdx.x;
    const int lane = t & 63;
    const int w    = t >> 6;
    const int wm   = w >> 1;
    const int wn   = w & 1;
    const int rowBase = blockIdx.y * 128;
    const int colBase = blockIdx.x * 128;

    const int c0 = t, c1 = t + 256;
    const int r0 = (c0 >> 6) * 16 + (c0 & 15);
    const int r1 = (c1 >> 6) * 16 + (c1 & 15);
    const int q0 = (c0 >> 4) & 3;
    const int q1 = (c1 >> 4) & 3;

    const int* gA0 = Aq + (size_t)(rowBase + r0) * KP + q0 * 8;
    const int* gA1 = Aq + (size_t)(rowBase + r1) * KP + q1 * 8;
    const int* gB0 = Bq + (size_t)(colBase + r0) * KP + q0 * 8;
    const int* gB1 = Bq + (size_t)(colBase + r1) * KP + q1 * 8;

    v4i* lA0 = (v4i*)(smemA + c0 * 16);
    v4i* lA1 = (v4i*)(smemA + c1 * 16);
    v4i* lB0 = (v4i*)(smemB + c0 * 16);
    v4i* lB1 = (v4i*)(smemB + c1 * 16);

    v4i acc[4][4] = {};

    for (int kb = 0; kb < K_DIM; kb += 64) {
        const int kp = kb >> 1;
        int4 a00 = *(const int4*)(gA0 + kp);
        int4 a01 = *(const int4*)(gA0 + kp + 4);
        int4 a10 = *(const int4*)(gA1 + kp);
        int4 a11 = *(const int4*)(gA1 + kp + 4);
        int4 b00 = *(const int4*)(gB0 + kp);
        int4 b01 = *(const int4*)(gB0 + kp + 4);
        int4 b10 = *(const int4*)(gB1 + kp);
        int4 b11 = *(const int4*)(gB1 + kp + 4);

        __syncthreads();

        unsigned u0, u1, u2, u3;
        unpack_group(a00, u0, u1); unpack_group(a01, u2, u3);
        *lA0 = (v4i){(int)u0, (int)u1, (int)u2, (int)u3};
        unpack_group(a10, u0, u1); unpack_group(a11, u2, u3);
        *lA1 = (v4i){(int)u0, (int)u1, (int)u2, (int)u3};
        unpack_group(b00, u0, u1); unpack_group(b01, u2, u3);
        *lB0 = (v4i){(int)u0, (int)u1, (int)u2, (int)u3};
        unpack_group(b10, u0, u1); unpack_group(b11, u2, u3);
        *lB1 = (v4i){(int)u0, (int)u1, (int)u2, (int)u3};

        __syncthreads();

        v4i af[4], bf[4];
        #pragma unroll
        for (int mt = 0; mt < 4; ++mt)
            af[mt] = *((const v4i*)(smemA + ((wm * 4 + mt) * 64 + lane) * 16));
        #pragma unroll
        for (int nt = 0; nt < 4; ++nt)
            bf[nt] = *((const v4i*)(smemB + ((wn * 4 + nt) * 64 + lane) * 16));

        #pragma unroll
        for (int mt = 0; mt < 4; ++mt)
            #pragma unroll
            for (int nt = 0; nt < 4; ++nt)
                acc[mt][nt] = __builtin_amdgcn_mfma_i32_16x16x64_i8(
                    af[mt], bf[nt], acc[mt][nt], 0, 0, 0);
    }

    const int ccol = lane & 15;
    const int crow = (lane >> 4) * 4;

    float xs[4][4];
    #pragma unroll
    for (int mt = 0; mt < 4; ++mt)
        #pragma unroll
        for (int r = 0; r < 4; ++r)
            xs[mt][r] = sx[rowBase + wm * 64 + mt * 16 + crow + r];

    #pragma unroll
    for (int nt = 0; nt < 4; ++nt) {
        const int gn = colBase + wn * 64 + nt * 16 + ccol;
        const float wsc = sw[gn];
        #pragma unroll
        for (int mt = 0; mt < 4; ++mt) {
            const int gm = rowBase + wm * 64 + mt * 16 + crow;
            #pragma unroll
            for (int r = 0; r < 4; ++r) {
                float v = (float)acc[mt][nt][r] * xs[mt][r] * wsc;
                out[(size_t)(gm + r) * N_DIM + gn] = v;
            }
        }
    }
}

extern "C" void kernel_launch(void* const* d_in, const int* in_sizes, int n_in,
                              void* d_out, int out_size, void* d_ws, size_t ws_size,
                              hipStream_t stream) {
    (void)in_sizes; (void)n_in; (void)out_size;
    const int*   x_q = (const int*)d_in[0];
    const float* sx  = (const float*)d_in[1];
    const int*   w_q = (const int*)d_in[2];
    const float* sw  = (const float*)d_in[3];
    float*       out = (float*)d_out;

    const size_t needA = (size_t)M_DIM * K_DIM;        // 16.8 MB
    const size_t needB = (size_t)N_DIM * K_DIM;        // 45.1 MB
    if (ws_size >= needA + needB) {
        unsigned char* A8 = (unsigned char*)d_ws;
        unsigned char* B8 = A8 + needA;
        const int n4A = M_DIM * KP / 4;   // 2,097,152
        const int n4B = N_DIM * KP / 4;   // 5,636,096
        const int n4T = n4A + n4B;        // 7,733,248
        unpack_i4_all<<<2048, 256, 0, stream>>>(x_q, w_q, (uint2*)d_ws, n4A, n4T);
        // 256x256 tiles: 43 x 16 = 688 blocks = 8 * 86 (XCD swizzle exact).
        gemm_i8_kernel<<<688, 512, 0, stream>>>(A8, B8, sx, sw, out);
    } else {
        dim3 grid(N_DIM / 128, M_DIM / 128);   // 86 x 32, exact
        gemm_i4_fused_kernel<<<grid, 256, 0, stream>>>(x_q, w_q, sx, sw, out);
    }
}